// Round 1
// baseline (3315.939 us; speedup 1.0000x reference)
//
#include <hip/hip_runtime.h>
#include <hip/hip_bf16.h>

// ---------------------------------------------------------------------------
// ASGNN: conv1 = SAGEConv(128->256)+relu ; conv2 = SAGEConv(256->1) ;
// attention conv is dead (softmax over size-1 axis == 1) ; out = mu + eps*exp(logvar)
//
// Pipeline:
//  K0 prep_w     : Wc[k][j] = stacked/transposed [W1l;W1r]  (256x256)
//  K1 scatter_x  : agg1[dst] += x[src] (atomics), cnt[dst] += 1
//  K2 gemm_fused : h = relu(A @ Wc + b1l); t = W2l.h, r = W2r.h (epilogue, atomics)
//  K3 scatter_t  : tsum[dst] += t[src]
//  K4 final      : z = tsum/max(cnt,1)+b2l+r ; out = z*Wmu+bmu + eps*exp(z*Wlv+blv)
// ---------------------------------------------------------------------------

#define F_DIM 128
#define H_DIM 256
#define BM 128
#define BJ 128
#define BK 64

__global__ void prep_w(const float* __restrict__ W1l, const float* __restrict__ W1r,
                       float* __restrict__ Wc) {
    int idx = blockIdx.x * blockDim.x + threadIdx.x;   // 65536
    int k = idx >> 8;
    int j = idx & 255;
    float v = (k < F_DIM) ? W1l[j * F_DIM + k] : W1r[j * F_DIM + (k - F_DIM)];
    Wc[k * H_DIM + j] = v;
}

__global__ void scatter_x(const float* __restrict__ x, const int* __restrict__ src,
                          const int* __restrict__ dst, float* __restrict__ agg1,
                          float* __restrict__ cnt, int E) {
    int gtid = blockIdx.x * blockDim.x + threadIdx.x;
    int e = gtid >> 5;          // 32 threads per edge (128 floats as float4)
    int q = gtid & 31;
    if (e >= E) return;
    int s = src[e];
    int d = dst[e];
    float4 v = *(const float4*)(x + (size_t)s * F_DIM + q * 4);
    float* ap = agg1 + (size_t)d * F_DIM + q * 4;
    atomicAdd(ap + 0, v.x);
    atomicAdd(ap + 1, v.y);
    atomicAdd(ap + 2, v.z);
    atomicAdd(ap + 3, v.w);
    if (q == 0) atomicAdd(&cnt[d], 1.0f);
}

__global__ __launch_bounds__(256, 2)
void gemm_fused(const float* __restrict__ x, const float* __restrict__ agg1,
                const float* __restrict__ cnt, const float* __restrict__ Wc,
                const float* __restrict__ b1l, const float* __restrict__ W2l,
                const float* __restrict__ W2r, float* __restrict__ t,
                float* __restrict__ r, int Nn) {
    __shared__ float As[BK][BM];   // 32 KB, [k][node]
    __shared__ float Bs[BK][BJ];   // 32 KB, [k][j]
    int mb = blockIdx.x >> 1;
    int jb = blockIdx.x & 1;
    int m0 = mb * BM;
    int tid = threadIdx.x;
    int ty = tid >> 4;   // 0..15 -> node group
    int tx = tid & 15;   // 0..15 -> output group

    float acc[8][8] = {};

    for (int k0 = 0; k0 < 2 * F_DIM; k0 += BK) {
        // stage A (transposed): 128 nodes x 64 k ; k<128 -> agg1/cnt, else x
        #pragma unroll
        for (int pass = 0; pass < 8; ++pass) {
            int node = (tid >> 4) + pass * 16;     // 0..127
            int kk = (tid & 15) * 4;               // 0..60
            int k = k0 + kk;
            int gn = m0 + node;
            float4 v = make_float4(0.f, 0.f, 0.f, 0.f);
            if (gn < Nn) {
                if (k < F_DIM) {
                    v = *(const float4*)(agg1 + (size_t)gn * F_DIM + k);
                    float inv = 1.0f / fmaxf(cnt[gn], 1.0f);
                    v.x *= inv; v.y *= inv; v.z *= inv; v.w *= inv;
                } else {
                    v = *(const float4*)(x + (size_t)gn * F_DIM + (k - F_DIM));
                }
            }
            As[kk + 0][node] = v.x;
            As[kk + 1][node] = v.y;
            As[kk + 2][node] = v.z;
            As[kk + 3][node] = v.w;
        }
        // stage B: 64 k x 128 j, coalesced copy (Wc already k-major)
        #pragma unroll
        for (int pass = 0; pass < 8; ++pass) {
            int idx = tid + pass * 256;            // float4 index, 0..2047
            int kk = idx >> 5;
            int j4 = idx & 31;
            float4 v = *(const float4*)(Wc + (size_t)(k0 + kk) * H_DIM + jb * BJ + j4 * 4);
            *(float4*)(&Bs[kk][j4 * 4]) = v;
        }
        __syncthreads();

        #pragma unroll 4
        for (int kk = 0; kk < BK; ++kk) {
            float4 a0 = *(const float4*)(&As[kk][ty * 8]);
            float4 a1 = *(const float4*)(&As[kk][ty * 8 + 4]);
            float4 b0 = *(const float4*)(&Bs[kk][tx * 8]);
            float4 b1 = *(const float4*)(&Bs[kk][tx * 8 + 4]);
            float a[8] = {a0.x, a0.y, a0.z, a0.w, a1.x, a1.y, a1.z, a1.w};
            float b[8] = {b0.x, b0.y, b0.z, b0.w, b1.x, b1.y, b1.z, b1.w};
            #pragma unroll
            for (int i = 0; i < 8; ++i)
                #pragma unroll
                for (int j = 0; j < 8; ++j)
                    acc[i][j] += a[i] * b[j];
        }
        __syncthreads();
    }

    // epilogue: h = relu(acc + b1l[j]); t += W2l.h ; r += W2r.h
    int jbase = jb * BJ + tx * 8;
    float w2l[8], w2r[8], bb[8];
    #pragma unroll
    for (int j = 0; j < 8; ++j) {
        w2l[j] = W2l[jbase + j];
        w2r[j] = W2r[jbase + j];
        bb[j]  = b1l[jbase + j];
    }
    #pragma unroll
    for (int i = 0; i < 8; ++i) {
        int gn = m0 + ty * 8 + i;
        if (gn < Nn) {
            float tp = 0.f, rp = 0.f;
            #pragma unroll
            for (int j = 0; j < 8; ++j) {
                float h = fmaxf(acc[i][j] + bb[j], 0.0f);
                tp += w2l[j] * h;
                rp += w2r[j] * h;
            }
            atomicAdd(&t[gn], tp);
            atomicAdd(&r[gn], rp);
        }
    }
}

__global__ void scatter_t(const float* __restrict__ t, const int* __restrict__ src,
                          const int* __restrict__ dst, float* __restrict__ tsum, int E) {
    int e = blockIdx.x * blockDim.x + threadIdx.x;
    if (e >= E) return;
    atomicAdd(&tsum[dst[e]], t[src[e]]);
}

__global__ void final_k(const float* __restrict__ tsum, const float* __restrict__ cnt,
                        const float* __restrict__ r, const float* __restrict__ b2l,
                        const float* __restrict__ Wmu, const float* __restrict__ bmu,
                        const float* __restrict__ Wlv, const float* __restrict__ blv,
                        const float* __restrict__ eps, float* __restrict__ out, int Nn) {
    int i = blockIdx.x * blockDim.x + threadIdx.x;
    if (i >= Nn) return;
    float z = tsum[i] / fmaxf(cnt[i], 1.0f) + b2l[0] + r[i];
    float mu = z * Wmu[0] + bmu[0];
    float lv = z * Wlv[0] + blv[0];
    out[i] = mu + eps[i] * expf(lv);
}

extern "C" void kernel_launch(void* const* d_in, const int* in_sizes, int n_in,
                              void* d_out, int out_size, void* d_ws, size_t ws_size,
                              hipStream_t stream) {
    const float* x   = (const float*)d_in[0];
    const int*   ei  = (const int*)d_in[1];
    const float* W1l = (const float*)d_in[2];
    const float* b1l = (const float*)d_in[3];
    const float* W1r = (const float*)d_in[4];
    const float* W2l = (const float*)d_in[5];
    const float* b2l = (const float*)d_in[6];
    const float* W2r = (const float*)d_in[7];
    // d_in[8..10] = Wal, bal, War : dead code (softmax over size-1 axis == 1)
    const float* Wmu = (const float*)d_in[11];
    const float* bmu = (const float*)d_in[12];
    const float* Wlv = (const float*)d_in[13];
    const float* blv = (const float*)d_in[14];
    const float* eps = (const float*)d_in[15];
    float* out = (float*)d_out;

    const int Nn = in_sizes[0] / F_DIM;   // 100000
    const int E  = in_sizes[1] / 2;       // 1600000
    const int* src = ei;
    const int* dst = ei + E;

    char* ws = (char*)d_ws;
    float* agg1 = (float*)(ws + 0);                     // N*128 floats
    float* cnt  = (float*)(ws + 51200000);              // N
    float* tv   = (float*)(ws + 51600000);              // N
    float* rv   = (float*)(ws + 52000000);              // N
    float* tsum = (float*)(ws + 52400000);              // N
    float* Wc   = (float*)(ws + 52800000);              // 256*256

    // zero agg1, cnt, t, r, tsum in one shot (contiguous)
    hipMemsetAsync(ws, 0, 52800000, stream);

    prep_w<<<256, 256, 0, stream>>>(W1l, W1r, Wc);

    {
        long long threads = (long long)E * 32;
        int blocks = (int)((threads + 255) / 256);
        scatter_x<<<blocks, 256, 0, stream>>>(x, src, dst, agg1, cnt, E);
    }

    {
        int mblocks = (Nn + BM - 1) / BM;
        gemm_fused<<<mblocks * 2, 256, 0, stream>>>(x, agg1, cnt, Wc, b1l, W2l, W2r,
                                                    tv, rv, Nn);
    }

    scatter_t<<<(E + 255) / 256, 256, 0, stream>>>(tv, src, dst, tsum, E);

    final_k<<<(Nn + 255) / 256, 256, 0, stream>>>(tsum, cnt, rv, b2l, Wmu, bmu,
                                                  Wlv, blv, eps, out, Nn);
}

// Round 2
// 884.730 us; speedup vs baseline: 3.7480x; 3.7480x over previous
//
#include <hip/hip_runtime.h>
#include <hip/hip_bf16.h>

// ---------------------------------------------------------------------------
// ASGNN: conv1 = SAGEConv(128->256)+relu ; conv2 = SAGEConv(256->1) ;
// attention conv is dead (softmax over size-1 axis == 1) ; out = mu + eps*exp(logvar)
//
// Round 2: replace scatter-atomics (3.3 GB HBM write traffic, 2758 us) with
// on-device CSR build + register-accumulating gather.
//
//  K0 prep_w      : Wc[k][j] = stacked/transposed [W1l;W1r]  (256x256)
//  K1 degree_k    : deg[dst]++ (int atomics, L2-resident)
//  K2 scan_k      : row_ptr = exclusive_scan(deg)  (single WG, wave scan)
//  K3 fill_k      : csr[atomicInc(cursor[dst])] = src
//  K4 gather_mean : agg[n] = mean_{s in nbr(n)} x[s]   (registers, no atomics)
//  K5 gemm_fused  : h = relu(agg|x @ Wc + b1l); t = W2l.h, r = W2r.h
//  K6 final_k     : z = mean_{s} t[s] + b2l + r ; out = mu + eps*exp(logvar)
// ---------------------------------------------------------------------------

#define F_DIM 128
#define H_DIM 256
#define BM 128
#define BJ 128
#define BK 64

__global__ void prep_w(const float* __restrict__ W1l, const float* __restrict__ W1r,
                       float* __restrict__ Wc) {
    int idx = blockIdx.x * blockDim.x + threadIdx.x;   // 65536
    int k = idx >> 8;
    int j = idx & 255;
    float v = (k < F_DIM) ? W1l[j * F_DIM + k] : W1r[j * F_DIM + (k - F_DIM)];
    Wc[k * H_DIM + j] = v;
}

__global__ void degree_k(const int* __restrict__ dst, int* __restrict__ deg, int E) {
    int e = blockIdx.x * blockDim.x + threadIdx.x;
    if (e >= E) return;
    atomicAdd(&deg[dst[e]], 1);
}

// single-workgroup exclusive scan (1024 threads, wave-shuffle inner scan)
__global__ __launch_bounds__(1024)
void scan_k(const int* __restrict__ deg, int* __restrict__ row_ptr,
            int* __restrict__ cursor, int Nn) {
    __shared__ int wsum[16];
    __shared__ int carry_s;
    int tid = threadIdx.x;
    int lane = tid & 63, w = tid >> 6;
    if (tid == 0) carry_s = 0;
    __syncthreads();
    for (int base = 0; base < Nn; base += 1024) {
        int i = base + tid;
        int v = (i < Nn) ? deg[i] : 0;
        int sc = v;
        #pragma unroll
        for (int off = 1; off < 64; off <<= 1) {
            int t = __shfl_up(sc, off, 64);
            if (lane >= off) sc += t;
        }
        if (lane == 63) wsum[w] = sc;
        __syncthreads();
        int woff = 0;
        for (int k = 0; k < w; ++k) woff += wsum[k];
        int excl = sc - v + woff + carry_s;
        if (i < Nn) { row_ptr[i] = excl; cursor[i] = excl; }
        __syncthreads();
        if (tid == 1023) carry_s = excl + v;   // running total
        __syncthreads();
    }
    if (tid == 0) row_ptr[Nn] = carry_s;
}

__global__ void fill_k(const int* __restrict__ src, const int* __restrict__ dst,
                       int* __restrict__ cursor, int* __restrict__ csr, int E) {
    int e = blockIdx.x * blockDim.x + threadIdx.x;
    if (e >= E) return;
    int p = atomicAdd(&cursor[dst[e]], 1);
    csr[p] = src[e];
}

// 8 nodes per 256-thread block; 32 threads own one float4 column each
__global__ __launch_bounds__(256)
void gather_mean(const float* __restrict__ x, const int* __restrict__ row_ptr,
                 const int* __restrict__ csr, float* __restrict__ agg, int Nn) {
    int node = blockIdx.x * 8 + (threadIdx.x >> 5);
    int q = threadIdx.x & 31;
    if (node >= Nn) return;
    int beg = row_ptr[node], end = row_ptr[node + 1];
    float4 a0 = make_float4(0.f, 0.f, 0.f, 0.f);
    float4 a1 = make_float4(0.f, 0.f, 0.f, 0.f);
    int j = beg;
    for (; j + 1 < end; j += 2) {
        int s0 = csr[j], s1 = csr[j + 1];
        float4 v0 = *(const float4*)(x + (size_t)s0 * F_DIM + q * 4);
        float4 v1 = *(const float4*)(x + (size_t)s1 * F_DIM + q * 4);
        a0.x += v0.x; a0.y += v0.y; a0.z += v0.z; a0.w += v0.w;
        a1.x += v1.x; a1.y += v1.y; a1.z += v1.z; a1.w += v1.w;
    }
    if (j < end) {
        int s0 = csr[j];
        float4 v0 = *(const float4*)(x + (size_t)s0 * F_DIM + q * 4);
        a0.x += v0.x; a0.y += v0.y; a0.z += v0.z; a0.w += v0.w;
    }
    float inv = 1.0f / fmaxf((float)(end - beg), 1.0f);
    float4 o;
    o.x = (a0.x + a1.x) * inv;
    o.y = (a0.y + a1.y) * inv;
    o.z = (a0.z + a1.z) * inv;
    o.w = (a0.w + a1.w) * inv;
    *(float4*)(agg + (size_t)node * F_DIM + q * 4) = o;
}

__global__ __launch_bounds__(256, 2)
void gemm_fused(const float* __restrict__ x, const float* __restrict__ agg,
                const float* __restrict__ Wc, const float* __restrict__ b1l,
                const float* __restrict__ W2l, const float* __restrict__ W2r,
                float* __restrict__ t, float* __restrict__ r, int Nn) {
    __shared__ float As[BK][BM];   // 32 KB, [k][node]
    __shared__ float Bs[BK][BJ];   // 32 KB, [k][j]
    int mb = blockIdx.x >> 1;
    int jb = blockIdx.x & 1;
    int m0 = mb * BM;
    int tid = threadIdx.x;
    int ty = tid >> 4;   // node group
    int tx = tid & 15;   // output group

    float acc[8][8] = {};

    for (int k0 = 0; k0 < 2 * F_DIM; k0 += BK) {
        #pragma unroll
        for (int pass = 0; pass < 8; ++pass) {
            int node = (tid >> 4) + pass * 16;
            int kk = (tid & 15) * 4;
            int k = k0 + kk;
            int gn = m0 + node;
            float4 v = make_float4(0.f, 0.f, 0.f, 0.f);
            if (gn < Nn) {
                if (k < F_DIM)
                    v = *(const float4*)(agg + (size_t)gn * F_DIM + k);
                else
                    v = *(const float4*)(x + (size_t)gn * F_DIM + (k - F_DIM));
            }
            As[kk + 0][node] = v.x;
            As[kk + 1][node] = v.y;
            As[kk + 2][node] = v.z;
            As[kk + 3][node] = v.w;
        }
        #pragma unroll
        for (int pass = 0; pass < 8; ++pass) {
            int idx = tid + pass * 256;
            int kk = idx >> 5;
            int j4 = idx & 31;
            float4 v = *(const float4*)(Wc + (size_t)(k0 + kk) * H_DIM + jb * BJ + j4 * 4);
            *(float4*)(&Bs[kk][j4 * 4]) = v;
        }
        __syncthreads();

        #pragma unroll 4
        for (int kk = 0; kk < BK; ++kk) {
            float4 a0 = *(const float4*)(&As[kk][ty * 8]);
            float4 a1 = *(const float4*)(&As[kk][ty * 8 + 4]);
            float4 b0 = *(const float4*)(&Bs[kk][tx * 8]);
            float4 b1 = *(const float4*)(&Bs[kk][tx * 8 + 4]);
            float a[8] = {a0.x, a0.y, a0.z, a0.w, a1.x, a1.y, a1.z, a1.w};
            float b[8] = {b0.x, b0.y, b0.z, b0.w, b1.x, b1.y, b1.z, b1.w};
            #pragma unroll
            for (int i = 0; i < 8; ++i)
                #pragma unroll
                for (int j = 0; j < 8; ++j)
                    acc[i][j] += a[i] * b[j];
        }
        __syncthreads();
    }

    int jbase = jb * BJ + tx * 8;
    float w2l[8], w2r[8], bb[8];
    #pragma unroll
    for (int j = 0; j < 8; ++j) {
        w2l[j] = W2l[jbase + j];
        w2r[j] = W2r[jbase + j];
        bb[j]  = b1l[jbase + j];
    }
    #pragma unroll
    for (int i = 0; i < 8; ++i) {
        int gn = m0 + ty * 8 + i;
        if (gn < Nn) {
            float tp = 0.f, rp = 0.f;
            #pragma unroll
            for (int j = 0; j < 8; ++j) {
                float h = fmaxf(acc[i][j] + bb[j], 0.0f);
                tp += w2l[j] * h;
                rp += w2r[j] * h;
            }
            atomicAdd(&t[gn], tp);
            atomicAdd(&r[gn], rp);
        }
    }
}

__global__ void final_k(const float* __restrict__ t, const int* __restrict__ row_ptr,
                        const int* __restrict__ csr, const float* __restrict__ r,
                        const float* __restrict__ b2l,
                        const float* __restrict__ Wmu, const float* __restrict__ bmu,
                        const float* __restrict__ Wlv, const float* __restrict__ blv,
                        const float* __restrict__ eps, float* __restrict__ out, int Nn) {
    int i = blockIdx.x * blockDim.x + threadIdx.x;
    if (i >= Nn) return;
    int beg = row_ptr[i], end = row_ptr[i + 1];
    float s = 0.f;
    for (int j = beg; j < end; ++j) s += t[csr[j]];
    float z = s / fmaxf((float)(end - beg), 1.0f) + b2l[0] + r[i];
    float mu = z * Wmu[0] + bmu[0];
    float lv = z * Wlv[0] + blv[0];
    out[i] = mu + eps[i] * expf(lv);
}

extern "C" void kernel_launch(void* const* d_in, const int* in_sizes, int n_in,
                              void* d_out, int out_size, void* d_ws, size_t ws_size,
                              hipStream_t stream) {
    const float* x   = (const float*)d_in[0];
    const int*   ei  = (const int*)d_in[1];
    const float* W1l = (const float*)d_in[2];
    const float* b1l = (const float*)d_in[3];
    const float* W1r = (const float*)d_in[4];
    const float* W2l = (const float*)d_in[5];
    const float* b2l = (const float*)d_in[6];
    const float* W2r = (const float*)d_in[7];
    // d_in[8..10] = Wal, bal, War : dead (softmax over size-1 axis == 1)
    const float* Wmu = (const float*)d_in[11];
    const float* bmu = (const float*)d_in[12];
    const float* Wlv = (const float*)d_in[13];
    const float* blv = (const float*)d_in[14];
    const float* eps = (const float*)d_in[15];
    float* out = (float*)d_out;

    const int Nn = in_sizes[0] / F_DIM;   // 100000
    const int E  = in_sizes[1] / 2;       // 1600000
    const int* src = ei;
    const int* dst = ei + E;

    char* ws = (char*)d_ws;
    int*   deg     = (int*)(ws + 0);           // N ints
    float* tv      = (float*)(ws + 400000);    // N
    float* rv      = (float*)(ws + 800000);    // N
    int*   row_ptr = (int*)(ws + 1200000);     // N+1
    int*   cursor  = (int*)(ws + 1600128);     // N
    int*   csr     = (int*)(ws + 2000128);     // E
    float* agg     = (float*)(ws + 8400128);   // N*128
    float* Wc      = (float*)(ws + 59600128);  // 256*256

    // zero deg, tv, rv (contiguous 1.2 MB)
    hipMemsetAsync(ws, 0, 1200000, stream);

    prep_w<<<256, 256, 0, stream>>>(W1l, W1r, Wc);

    degree_k<<<(E + 255) / 256, 256, 0, stream>>>(dst, deg, E);
    scan_k<<<1, 1024, 0, stream>>>(deg, row_ptr, cursor, Nn);
    fill_k<<<(E + 255) / 256, 256, 0, stream>>>(src, dst, cursor, csr, E);

    gather_mean<<<(Nn + 7) / 8, 256, 0, stream>>>(x, row_ptr, csr, agg, Nn);

    {
        int mblocks = (Nn + BM - 1) / BM;
        gemm_fused<<<mblocks * 2, 256, 0, stream>>>(x, agg, Wc, b1l, W2l, W2r,
                                                    tv, rv, Nn);
    }

    final_k<<<(Nn + 255) / 256, 256, 0, stream>>>(tv, row_ptr, csr, rv, b2l,
                                                  Wmu, bmu, Wlv, blv, eps, out, Nn);
}

// Round 3
// 363.431 us; speedup vs baseline: 9.1240x; 2.4344x over previous
//
#include <hip/hip_runtime.h>
#include <hip/hip_bf16.h>

// ---------------------------------------------------------------------------
// ASGNN round 3: bf16 MFMA GEMM + bf16 gather.
//  K0 cvt_x       : xb = bf16(x)
//  K1 prep_w      : Wb[j][k] = bf16 of stacked [W1l | W1r] rows (j-major)
//  K2 degree_k    : deg[dst]++
//  K3 scan_blk/top/add : row_ptr = exscan(deg), cursor = row_ptr
//  K4 fill_k      : csr[cursor[dst]++] = src
//  K5 gather_mean : aggb[n] = bf16(mean_{s in nbr(n)} xb[s])
//  K6 gemm_mfma   : h = relu([aggb|xb] @ Wb^T + b1l); t=W2l.h, r=W2r.h fused
//  K7 final_k     : z = mean_s t[s] + b2l + r ; out = mu + eps*exp(logvar)
// ---------------------------------------------------------------------------

#define F_DIM 128
#define NFEAT2 256

typedef __bf16 b8 __attribute__((ext_vector_type(8)));
typedef float  f4 __attribute__((ext_vector_type(4)));

__device__ inline float bf2f(unsigned short u) {
    unsigned int v = ((unsigned int)u) << 16;
    return __uint_as_float(v);
}
__device__ inline unsigned short f2bf(float f) {
    unsigned int u = __float_as_uint(f);
    u += 0x7fffu + ((u >> 16) & 1u);
    return (unsigned short)(u >> 16);
}

__global__ void cvt_x(const float* __restrict__ x, unsigned short* __restrict__ xb, int n4) {
    int i = blockIdx.x * blockDim.x + threadIdx.x;
    if (i >= n4) return;
    float4 v = *(const float4*)(x + (size_t)i * 4);
    ushort4 o;
    o.x = f2bf(v.x); o.y = f2bf(v.y); o.z = f2bf(v.z); o.w = f2bf(v.w);
    *(ushort4*)(xb + (size_t)i * 4) = o;
}

__global__ void prep_w(const float* __restrict__ W1l, const float* __restrict__ W1r,
                       unsigned short* __restrict__ Wb) {
    int idx = blockIdx.x * blockDim.x + threadIdx.x;   // 65536
    int j = idx >> 8;
    int k = idx & 255;
    float v = (k < F_DIM) ? W1l[j * F_DIM + k] : W1r[j * F_DIM + (k - F_DIM)];
    Wb[j * NFEAT2 + k] = f2bf(v);
}

__global__ void degree_k(const int* __restrict__ dst, int* __restrict__ deg, int E) {
    int e = blockIdx.x * blockDim.x + threadIdx.x;
    if (e >= E) return;
    atomicAdd(&deg[dst[e]], 1);
}

__global__ __launch_bounds__(1024)
void scan_blk(const int* __restrict__ deg, int* __restrict__ row_ptr,
              int* __restrict__ bsum, int Nn) {
    __shared__ int wsum[16];
    int tid = threadIdx.x, lane = tid & 63, w = tid >> 6;
    int i = blockIdx.x * 1024 + tid;
    int v = (i < Nn) ? deg[i] : 0;
    int sc = v;
    #pragma unroll
    for (int off = 1; off < 64; off <<= 1) {
        int t = __shfl_up(sc, off, 64);
        if (lane >= off) sc += t;
    }
    if (lane == 63) wsum[w] = sc;
    __syncthreads();
    int woff = 0;
    for (int k = 0; k < w; ++k) woff += wsum[k];
    if (i < Nn) row_ptr[i] = sc - v + woff;     // block-local exclusive
    if (tid == 1023) bsum[blockIdx.x] = woff + sc;
}

__global__ __launch_bounds__(128)
void scan_top(const int* __restrict__ bsum, int* __restrict__ boff,
              int* __restrict__ row_ptr, int nb, int Nn) {
    __shared__ int ws2[2];
    int tid = threadIdx.x, lane = tid & 63, w = tid >> 6;
    int v = (tid < nb) ? bsum[tid] : 0;
    int sc = v;
    #pragma unroll
    for (int off = 1; off < 64; off <<= 1) {
        int t = __shfl_up(sc, off, 64);
        if (lane >= off) sc += t;
    }
    if (lane == 63) ws2[w] = sc;
    __syncthreads();
    int woff = (w == 1) ? ws2[0] : 0;
    if (tid < nb) boff[tid] = sc - v + woff;
    __syncthreads();
    if (tid == 0) row_ptr[Nn] = ws2[0] + ws2[1];
}

__global__ void scan_add(int* __restrict__ row_ptr, int* __restrict__ cursor,
                         const int* __restrict__ boff, int Nn) {
    int i = blockIdx.x * blockDim.x + threadIdx.x;
    if (i >= Nn) return;
    int v = row_ptr[i] + boff[i >> 10];
    row_ptr[i] = v;
    cursor[i] = v;
}

__global__ void fill_k(const int* __restrict__ src, const int* __restrict__ dst,
                       int* __restrict__ cursor, int* __restrict__ csr, int E) {
    int e = blockIdx.x * blockDim.x + threadIdx.x;
    if (e >= E) return;
    int p = atomicAdd(&cursor[dst[e]], 1);
    csr[p] = src[e];
}

// 16 nodes per 256-thread block; 16 lanes/node, 16B (8 bf16) per lane
__global__ __launch_bounds__(256)
void gather_mean(const unsigned short* __restrict__ xb, const int* __restrict__ row_ptr,
                 const int* __restrict__ csr, unsigned short* __restrict__ aggb, int Nn) {
    int node = blockIdx.x * 16 + (threadIdx.x >> 4);
    int q = threadIdx.x & 15;
    if (node >= Nn) return;
    int beg = row_ptr[node], end = row_ptr[node + 1];
    float a[8] = {};
    int j = beg;
    for (; j + 1 < end; j += 2) {
        int s0 = csr[j], s1 = csr[j + 1];
        uint4 r0 = *(const uint4*)(xb + (size_t)s0 * F_DIM + q * 8);
        uint4 r1 = *(const uint4*)(xb + (size_t)s1 * F_DIM + q * 8);
        a[0] += bf2f(r0.x & 0xffff) + bf2f(r1.x & 0xffff);
        a[1] += bf2f(r0.x >> 16)    + bf2f(r1.x >> 16);
        a[2] += bf2f(r0.y & 0xffff) + bf2f(r1.y & 0xffff);
        a[3] += bf2f(r0.y >> 16)    + bf2f(r1.y >> 16);
        a[4] += bf2f(r0.z & 0xffff) + bf2f(r1.z & 0xffff);
        a[5] += bf2f(r0.z >> 16)    + bf2f(r1.z >> 16);
        a[6] += bf2f(r0.w & 0xffff) + bf2f(r1.w & 0xffff);
        a[7] += bf2f(r0.w >> 16)    + bf2f(r1.w >> 16);
    }
    if (j < end) {
        int s0 = csr[j];
        uint4 r0 = *(const uint4*)(xb + (size_t)s0 * F_DIM + q * 8);
        a[0] += bf2f(r0.x & 0xffff);
        a[1] += bf2f(r0.x >> 16);
        a[2] += bf2f(r0.y & 0xffff);
        a[3] += bf2f(r0.y >> 16);
        a[4] += bf2f(r0.z & 0xffff);
        a[5] += bf2f(r0.z >> 16);
        a[6] += bf2f(r0.w & 0xffff);
        a[7] += bf2f(r0.w >> 16);
    }
    float inv = 1.0f / fmaxf((float)(end - beg), 1.0f);
    uint4 o;
    o.x = (unsigned)f2bf(a[0] * inv) | ((unsigned)f2bf(a[1] * inv) << 16);
    o.y = (unsigned)f2bf(a[2] * inv) | ((unsigned)f2bf(a[3] * inv) << 16);
    o.z = (unsigned)f2bf(a[4] * inv) | ((unsigned)f2bf(a[5] * inv) << 16);
    o.w = (unsigned)f2bf(a[6] * inv) | ((unsigned)f2bf(a[7] * inv) << 16);
    *(uint4*)(aggb + (size_t)node * F_DIM + q * 8) = o;
}

// 128x128 tile, K=256 in 4 steps of 64. 4 waves (2x2), each 64x64 output.
// A = [aggb | xb] rows (bf16), B = Wb[j][k] (j-major bf16).
// LDS XOR-swizzle (T2): byte ^= (row&7)<<4.
__global__ __launch_bounds__(256)
void gemm_mfma(const unsigned short* __restrict__ aggb, const unsigned short* __restrict__ xb,
               const unsigned short* __restrict__ Wb, const float* __restrict__ b1l,
               const float* __restrict__ W2l, const float* __restrict__ W2r,
               float* __restrict__ tv, float* __restrict__ rv, int Nn) {
    __shared__ unsigned short Al[128 * 64];   // 16 KB
    __shared__ unsigned short Bl[128 * 64];   // 16 KB
    int mb = blockIdx.x >> 1;
    int jb = blockIdx.x & 1;
    int m0 = mb * 128;
    int tid = threadIdx.x;
    int lane = tid & 63, wid = tid >> 6;
    int wm = wid >> 1, wj = wid & 1;

    f4 acc[4][4] = {};

    for (int kstep = 0; kstep < 4; ++kstep) {
        const unsigned short* Asrc = (kstep < 2) ? aggb : xb;
        int kbase = (kstep & 1) * 64;
        // stage A: 128 rows x 64 k (16 KB) as 1024 16B chunks
        #pragma unroll
        for (int pass = 0; pass < 4; ++pass) {
            int c = tid + pass * 256;
            int m = c >> 3, kc = c & 7;
            int gn = m0 + m;
            uint4 v = make_uint4(0u, 0u, 0u, 0u);
            if (gn < Nn) v = *(const uint4*)(Asrc + (size_t)gn * F_DIM + kbase + kc * 8);
            int byte = (m * 128 + kc * 16) ^ ((m & 7) << 4);
            *(uint4*)((char*)Al + byte) = v;
        }
        // stage B: 128 cols x 64 k
        #pragma unroll
        for (int pass = 0; pass < 4; ++pass) {
            int c = tid + pass * 256;
            int jj = c >> 3, kc = c & 7;
            uint4 v = *(const uint4*)(Wb + (size_t)(jb * 128 + jj) * NFEAT2 + kstep * 64 + kc * 8);
            int byte = (jj * 128 + kc * 16) ^ ((jj & 7) << 4);
            *(uint4*)((char*)Bl + byte) = v;
        }
        __syncthreads();

        #pragma unroll
        for (int ks = 0; ks < 2; ++ks) {
            int kk2 = (ks * 32 + ((lane >> 4) << 3)) * 2;   // byte offset in row
            b8 af[4], bfr[4];
            #pragma unroll
            for (int fm = 0; fm < 4; ++fm) {
                int m = (wm << 6) + (fm << 4) + (lane & 15);
                int byte = (m * 128 + kk2) ^ ((m & 7) << 4);
                af[fm] = *(const b8*)((const char*)Al + byte);
            }
            #pragma unroll
            for (int fj = 0; fj < 4; ++fj) {
                int jj = (wj << 6) + (fj << 4) + (lane & 15);
                int byte = (jj * 128 + kk2) ^ ((jj & 7) << 4);
                bfr[fj] = *(const b8*)((const char*)Bl + byte);
            }
            #pragma unroll
            for (int fm = 0; fm < 4; ++fm)
                #pragma unroll
                for (int fj = 0; fj < 4; ++fj)
                    acc[fm][fj] = __builtin_amdgcn_mfma_f32_16x16x32_bf16(
                        af[fm], bfr[fj], acc[fm][fj], 0, 0, 0);
        }
        __syncthreads();
    }

    // epilogue: h = relu(acc + b1l[j]); reduce w2l.h / w2r.h over j
    float bb[4], wl[4], wr[4];
    #pragma unroll
    for (int fj = 0; fj < 4; ++fj) {
        int j_abs = jb * 128 + (wj << 6) + (fj << 4) + (lane & 15);
        bb[fj] = b1l[j_abs];
        wl[fj] = W2l[j_abs];
        wr[fj] = W2r[j_abs];
    }
    #pragma unroll
    for (int fm = 0; fm < 4; ++fm) {
        #pragma unroll
        for (int reg = 0; reg < 4; ++reg) {
            int row = m0 + (wm << 6) + (fm << 4) + ((lane >> 4) << 2) + reg;
            float tp = 0.f, rp = 0.f;
            #pragma unroll
            for (int fj = 0; fj < 4; ++fj) {
                float h = fmaxf(acc[fm][fj][reg] + bb[fj], 0.0f);
                tp += wl[fj] * h;
                rp += wr[fj] * h;
            }
            #pragma unroll
            for (int mask = 1; mask < 16; mask <<= 1) {
                tp += __shfl_xor(tp, mask, 64);
                rp += __shfl_xor(rp, mask, 64);
            }
            if ((lane & 15) == 0 && row < Nn) {
                atomicAdd(&tv[row], tp);
                atomicAdd(&rv[row], rp);
            }
        }
    }
}

__global__ void final_k(const float* __restrict__ t, const int* __restrict__ row_ptr,
                        const int* __restrict__ csr, const float* __restrict__ r,
                        const float* __restrict__ b2l,
                        const float* __restrict__ Wmu, const float* __restrict__ bmu,
                        const float* __restrict__ Wlv, const float* __restrict__ blv,
                        const float* __restrict__ eps, float* __restrict__ out, int Nn) {
    int i = blockIdx.x * blockDim.x + threadIdx.x;
    if (i >= Nn) return;
    int beg = row_ptr[i], end = row_ptr[i + 1];
    float s = 0.f;
    for (int j = beg; j < end; ++j) s += t[csr[j]];
    float z = s / fmaxf((float)(end - beg), 1.0f) + b2l[0] + r[i];
    float mu = z * Wmu[0] + bmu[0];
    float lv = z * Wlv[0] + blv[0];
    out[i] = mu + eps[i] * expf(lv);
}

extern "C" void kernel_launch(void* const* d_in, const int* in_sizes, int n_in,
                              void* d_out, int out_size, void* d_ws, size_t ws_size,
                              hipStream_t stream) {
    const float* x   = (const float*)d_in[0];
    const int*   ei  = (const int*)d_in[1];
    const float* W1l = (const float*)d_in[2];
    const float* b1l = (const float*)d_in[3];
    const float* W1r = (const float*)d_in[4];
    const float* W2l = (const float*)d_in[5];
    const float* b2l = (const float*)d_in[6];
    const float* W2r = (const float*)d_in[7];
    // d_in[8..10] = Wal, bal, War : dead (softmax over size-1 axis == 1)
    const float* Wmu = (const float*)d_in[11];
    const float* bmu = (const float*)d_in[12];
    const float* Wlv = (const float*)d_in[13];
    const float* blv = (const float*)d_in[14];
    const float* eps = (const float*)d_in[15];
    float* out = (float*)d_out;

    const int Nn = in_sizes[0] / F_DIM;   // 100000
    const int E  = in_sizes[1] / 2;       // 1600000
    const int* src = ei;
    const int* dst = ei + E;

    char* ws = (char*)d_ws;
    int*            deg     = (int*)(ws + 0);              // N
    float*          tv      = (float*)(ws + 400000);       // N
    float*          rv      = (float*)(ws + 800000);       // N
    int*            row_ptr = (int*)(ws + 1200000);        // N+1
    int*            cursor  = (int*)(ws + 1600016);        // N
    int*            bsum    = (int*)(ws + 2000016);        // <=1024
    int*            boff    = (int*)(ws + 2001040);        // <=1024
    int*            csr     = (int*)(ws + 2002064);        // E
    unsigned short* xb      = (unsigned short*)(ws + 8402064);   // N*128 bf16
    unsigned short* aggb    = (unsigned short*)(ws + 34002064);  // N*128 bf16
    unsigned short* Wb      = (unsigned short*)(ws + 59602064);  // 256*256 bf16

    hipMemsetAsync(ws, 0, 1200000, stream);   // deg, tv, rv

    cvt_x<<<(Nn * F_DIM / 4 + 255) / 256, 256, 0, stream>>>(x, xb, Nn * F_DIM / 4);
    prep_w<<<256, 256, 0, stream>>>(W1l, W1r, Wb);

    degree_k<<<(E + 255) / 256, 256, 0, stream>>>(dst, deg, E);
    int nb = (Nn + 1023) / 1024;
    scan_blk<<<nb, 1024, 0, stream>>>(deg, row_ptr, bsum, Nn);
    scan_top<<<1, 128, 0, stream>>>(bsum, boff, row_ptr, nb, Nn);
    scan_add<<<(Nn + 255) / 256, 256, 0, stream>>>(row_ptr, cursor, boff, Nn);
    fill_k<<<(E + 255) / 256, 256, 0, stream>>>(src, dst, cursor, csr, E);

    gather_mean<<<(Nn + 15) / 16, 256, 0, stream>>>(xb, row_ptr, csr, aggb, Nn);

    {
        int mblocks = (Nn + 127) / 128;
        gemm_mfma<<<mblocks * 2, 256, 0, stream>>>(aggb, xb, Wb, b1l, W2l, W2r,
                                                   tv, rv, Nn);
    }

    final_k<<<(Nn + 255) / 256, 256, 0, stream>>>(tv, row_ptr, csr, rv, b2l,
                                                  Wmu, bmu, Wlv, blv, eps, out, Nn);
}